// Round 12
// baseline (92.139 us; speedup 1.0000x reference)
//
#include <hip/hip_runtime.h>
#include <hip/hip_bf16.h>
#include <cstdint>

namespace {

constexpr int NPIX = 12544;   // 4*56*56

typedef __attribute__((ext_vector_type(8))) short bf16x8;
typedef __attribute__((ext_vector_type(4))) float f32x4;
typedef __attribute__((ext_vector_type(16))) float f32x16;
typedef _Float16 h2 __attribute__((ext_vector_type(2)));

__device__ __forceinline__ float wsum(float v) {
#pragma unroll
  for (int m = 32; m; m >>= 1) v += __shfl_xor(v, m, 64);
  return v;
}

__device__ __forceinline__ uint16_t f2bf(float f) {
  uint32_t u = __builtin_bit_cast(uint32_t, f);
  u += 0x7fffu + ((u >> 16) & 1u);
  return (uint16_t)(u >> 16);
}
__device__ __forceinline__ uint32_t packbf(float a, float b) {
  return (uint32_t)f2bf(a) | ((uint32_t)f2bf(b) << 16);
}
__device__ __forceinline__ ushort f2h(float f) {
  _Float16 h = (_Float16)f;
  return __builtin_bit_cast(ushort, h);
}
__device__ __forceinline__ float h2f(ushort u) {
  return (float)__builtin_bit_cast(_Float16, u);
}
__device__ __forceinline__ h2 bch2(uint32_t u) { return __builtin_bit_cast(h2, u); }

__device__ __forceinline__ float gelu_fast(float v) {
  float u = 0.7978845608028654f * (v + 0.044715f * v * v * v);
  float e = __expf(2.f * u);
  float th = 1.f - 2.f * __builtin_amdgcn_rcpf(e + 1.f);
  return 0.5f * v * (1.f + th);
}

// ---------------- Prep: convert+transpose all weights to bf16 ----------------
__global__ __launch_bounds__(256) void k_prep(
    const float* __restrict__ nqkv, const float* __restrict__ nproj,
    const float* __restrict__ nf1, const float* __restrict__ nf2,
    const float* __restrict__ gqkv, const float* __restrict__ gf1,
    const float* __restrict__ gf2, ushort* __restrict__ wT) {
  int t = blockIdx.x * 256 + threadIdx.x;
  if (t >= 201728) return;
  int i = t;
  if (i < 41472) {
    int br = i / 13824, r = i % 13824, n = r / 72, k = r % 72;
    wT[t] = k < 64 ? f2bf(nqkv[(br * 64 + k) * 192 + n]) : (ushort)0;
    return;
  }
  i -= 41472;
  if (i < 13824) {
    int br = i / 4608, r = i % 4608, n = r / 72, k = r % 72;
    wT[t] = k < 64 ? f2bf(nproj[(br * 64 + k) * 64 + n]) : (ushort)0;
    return;
  }
  i -= 13824;
  if (i < 55296) {
    int br = i / 18432, r = i % 18432, n = r / 72, k = r % 72;
    wT[t] = k < 64 ? f2bf(nf1[(br * 64 + k) * 256 + n]) : (ushort)0;
    return;
  }
  i -= 55296;
  if (i < 50688) {
    int br = i / 16896, r = i % 16896, n = r / 264, k = r % 264;
    wT[t] = k < 256 ? f2bf(nf2[(br * 256 + k) * 64 + n]) : (ushort)0;
    return;
  }
  i -= 50688;
  if (i < 13824) {
    int n = i / 72, k = i % 72;
    wT[t] = k < 64 ? f2bf(gqkv[k * 192 + n]) : (ushort)0;
    return;
  }
  i -= 13824;
  if (i < 13824) {
    int n = i / 72, k = i % 72;
    wT[t] = k < 64 ? f2bf(gf1[k * 192 + n]) : (ushort)0;
    return;
  }
  i -= 13824;
  {
    int n = i / 200, k = i % 200;
    wT[t] = k < 192 ? f2bf(gf2[k * 64 + n]) : (ushort)0;
  }
}

// ---------------- Kernel A: fused QKV — NAT (0..587) | GA (588..636) | pad (637)
__global__ __launch_bounds__(256) void k_qkv(
    const float* __restrict__ x, const float* __restrict__ nat_ln1_g,
    const float* __restrict__ nat_ln1_b, const ushort* __restrict__ wT,
    const float* __restrict__ nat_qkv_b, ushort* __restrict__ qn,
    ushort* __restrict__ kvn, const float* __restrict__ ga_ln1_g,
    const float* __restrict__ ga_ln1_b, const float* __restrict__ ga_qkv_b,
    ushort* __restrict__ qb, ushort* __restrict__ kb, ushort* __restrict__ vT) {
  __shared__ __align__(16) ushort sA[64 * 72];
  int bid = blockIdx.x;
  int tid = threadIdx.x, lane = tid & 63, wid = tid >> 6;
  if (bid == 637) {
    for (int i = tid; i < 4096; i += 256) {
      int bh = i >> 8, rem = i & 255;
      int n = 784 + (rem >> 4), d = rem & 15;
      qb[((size_t)bh * 800 + n) * 16 + d] = 0;
      kb[((size_t)bh * 800 + n) * 16 + d] = 0;
      vT[((size_t)bh * 16 + d) * 800 + n] = 0;
    }
    return;
  }
  int lr = lane & 15, lk = (lane >> 4) * 8;
  if (bid < 588) {  // NAT LN1 + QKV
    int br = bid / 196, grp = bid % 196;
    const ushort* Wg = wT + br * 13824;
    float g = nat_ln1_g[br * 64 + lane], bb = nat_ln1_b[br * 64 + lane];
#pragma unroll
    for (int i = 0; i < 16; ++i) {
      int pl = wid * 16 + i;
      float v = x[(size_t)(grp * 64 + pl) * 256 + br * 64 + lane];
      float s1 = wsum(v), s2 = wsum(v * v);
      float m = s1 * (1.f / 64.f);
      float var = s2 * (1.f / 64.f) - m * m;
      sA[pl * 72 + lane] = f2bf((v - m) * rsqrtf(var + 1e-5f) * g + bb);
    }
    __syncthreads();
    int m0 = wid * 16;
    bf16x8 a0 = *(const bf16x8*)&sA[(m0 + lr) * 72 + lk];
    bf16x8 a1 = *(const bf16x8*)&sA[(m0 + lr) * 72 + 32 + lk];
    int r0 = m0 + (lane >> 4) * 4;
#pragma unroll
    for (int nt = 0; nt < 12; ++nt) {
      int n0 = nt * 16;
      bf16x8 b0 = *(const bf16x8*)&Wg[(n0 + lr) * 72 + lk];
      bf16x8 b1 = *(const bf16x8*)&Wg[(n0 + lr) * 72 + 32 + lk];
      f32x4 acc = {0.f, 0.f, 0.f, 0.f};
      acc = __builtin_amdgcn_mfma_f32_16x16x32_bf16(a0, b0, acc, 0, 0, 0);
      acc = __builtin_amdgcn_mfma_f32_16x16x32_bf16(a1, b1, acc, 0, 0, 0);
      int col = n0 + lr;
      float bias = nat_qkv_b[br * 192 + col];
      if (nt < 4) {
        ushort* op = qn + ((size_t)br * NPIX + grp * 64 + r0) * 64 + col;
#pragma unroll
        for (int r = 0; r < 4; ++r) op[r * 64] = f2h((acc[r] + bias) * 0.25f);
      } else {
        ushort* op = kvn + ((size_t)br * NPIX + grp * 64 + r0) * 128 + (col - 64);
#pragma unroll
        for (int r = 0; r < 4; ++r) op[r * 128] = f2h(acc[r] + bias);
      }
    }
  } else {  // GA pool+LN + QKV via MFMA (49 blocks x 64 tokens)
    int g64 = bid - 588;
    const ushort* Wg = wT + 161280;
    float gg = ga_ln1_g[lane], bb = ga_ln1_b[lane];
#pragma unroll
    for (int i = 0; i < 16; ++i) {
      int tl = wid * 16 + i;
      int token = g64 * 64 + tl;
      int b = token / 784, rem2 = token % 784, hp = rem2 / 28, wp = rem2 % 28;
      float s = 0.f;
#pragma unroll
      for (int dy = 0; dy < 2; ++dy)
#pragma unroll
        for (int dxx = 0; dxx < 2; ++dxx) {
          int pix = b * 3136 + (hp * 2 + dy) * 56 + (wp * 2 + dxx);
          float v = x[(size_t)pix * 256 + 192 + lane];
          float s1 = wsum(v), s2 = wsum(v * v);
          float m = s1 * (1.f / 64.f);
          float var = s2 * (1.f / 64.f) - m * m;
          s += (v - m) * rsqrtf(var + 1e-5f) * gg + bb;
        }
      sA[tl * 72 + lane] = f2bf(0.25f * s);
    }
    __syncthreads();
    int m0 = wid * 16;
    bf16x8 a0 = *(const bf16x8*)&sA[(m0 + lr) * 72 + lk];
    bf16x8 a1 = *(const bf16x8*)&sA[(m0 + lr) * 72 + 32 + lk];
    int r0 = m0 + (lane >> 4) * 4;
#pragma unroll
    for (int nt = 0; nt < 12; ++nt) {
      int n0 = nt * 16;
      bf16x8 b0 = *(const bf16x8*)&Wg[(n0 + lr) * 72 + lk];
      bf16x8 b1 = *(const bf16x8*)&Wg[(n0 + lr) * 72 + 32 + lk];
      f32x4 acc = {0.f, 0.f, 0.f, 0.f};
      acc = __builtin_amdgcn_mfma_f32_16x16x32_bf16(a0, b0, acc, 0, 0, 0);
      acc = __builtin_amdgcn_mfma_f32_16x16x32_bf16(a1, b1, acc, 0, 0, 0);
      int col = n0 + lr;
      float bias = ga_qkv_b[col];
      int hh = (col & 63) >> 4, d = col & 15;
#pragma unroll
      for (int r = 0; r < 4; ++r) {
        int token = g64 * 64 + r0 + r;
        int b = token / 784, nn = token % 784;
        float v = acc[r] + bias;
        if (col < 64)
          qb[((size_t)(b * 4 + hh) * 800 + nn) * 16 + d] = f2bf(v * 0.25f);
        else if (col < 128)
          kb[((size_t)(b * 4 + hh) * 800 + nn) * 16 + d] = f2bf(v);
        else
          vT[((size_t)(b * 4 + hh) * 16 + d) * 800 + nn] = f2bf(v);
      }
    }
  }
}

// ---------------- Kernel B: NAT fully-fused block (attn+proj+LN2+MLP) | GA attn
// LDS union (26656 ushorts = 53,312 B):
//   phase 1: sKV [196][136]
//   phase 2: sX @0 (64*72), sH @4608 (64*264), attn-out/x1f @21504 (64*72)
__global__ __launch_bounds__(256) void k_attn(
    const ushort* __restrict__ qn, const ushort* __restrict__ kvn,
    const float* __restrict__ rpb, const ushort* __restrict__ wT,
    const float* __restrict__ pb, const float* __restrict__ x,
    const float* __restrict__ nat_ln2_g, const float* __restrict__ nat_ln2_b,
    const float* __restrict__ nat_f1b, const float* __restrict__ nat_f2b,
    float* __restrict__ out, const ushort* __restrict__ qb,
    const ushort* __restrict__ kb, const ushort* __restrict__ vT,
    float* __restrict__ x1g) {
  __shared__ __align__(16) ushort sBuf[196 * 136];
  int bid = blockIdx.x;
  int tid = threadIdx.x, lane = tid & 63, wid = tid >> 6;
  if (bid < 588) {
    ushort* sKV = sBuf;
    int br = bid / 196, rem = bid % 196;
    int b = rem / 49, t = rem % 49;
    int y0 = (t / 7) * 8, x0 = (t % 7) * 8;
    int hy = min(max(y0 - 3, 0), 42), hx = min(max(x0 - 3, 0), 42);
    const ushort* kvbase = kvn + ((size_t)br * NPIX + b * 3136) * 128;
    for (int i = tid; i < 3136; i += 256) {
      int p = i >> 4, c = i & 15;
      int py = p / 14, px = p % 14;
      int gp = (hy + py) * 56 + (hx + px);
      uint4 v = *(const uint4*)&kvbase[(size_t)gp * 128 + c * 8];
      *(uint4*)&sKV[p * 136 + c * 8] = v;
    }
    __syncthreads();
    int pl = tid & 63, h = tid >> 6;
    int ly = pl >> 3, lx = pl & 7;
    int y = y0 + ly, xg = x0 + lx;
    int sy = min(max(y - 3, 0), 49), sx = min(max(xg - 3, 0), 49);
    int by = sy - hy, bx = sx - hx;
    int gpix = b * 3136 + y * 56 + xg;
    const ushort* qp = qn + ((size_t)br * NPIX + gpix) * 64 + h * 16;
    uint4 qv0 = *(const uint4*)&qp[0];
    uint4 qv1 = *(const uint4*)&qp[8];
    h2 q[8] = {bch2(qv0.x), bch2(qv0.y), bch2(qv0.z), bch2(qv0.w),
               bch2(qv1.x), bch2(qv1.y), bch2(qv1.z), bch2(qv1.w)};
    const float* rp = rpb + (br * 4 + h) * 169 + (sy - y + 6) * 13 + (sx - xg + 6);
    h2 z = {(_Float16)0.f, (_Float16)0.f};
    // pass 1: 49 scores in registers + exact max
    float s[49];
    float mx = -1e30f;
#pragma unroll
    for (int a = 0; a < 7; ++a) {
      const ushort* krow = &sKV[((by + a) * 14 + bx) * 136 + h * 16];
      const float* rpa = rp + a * 13;
#pragma unroll
      for (int c = 0; c < 7; ++c) {
        const ushort* kp = krow + c * 136;
        uint4 k0 = *(const uint4*)&kp[0];
        uint4 k1 = *(const uint4*)&kp[8];
        h2 d = z;
        d = bch2(k0.x) * q[0] + d;
        d = bch2(k0.y) * q[1] + d;
        d = bch2(k0.z) * q[2] + d;
        d = bch2(k0.w) * q[3] + d;
        d = bch2(k1.x) * q[4] + d;
        d = bch2(k1.y) * q[5] + d;
        d = bch2(k1.z) * q[6] + d;
        d = bch2(k1.w) * q[7] + d;
        float sd = (float)d[0] + (float)d[1] + rpa[c];
        s[a * 7 + c] = sd;
        mx = fmaxf(mx, sd);
      }
    }
    // pass 2: independent exps + V accumulation
    float l = 0.f;
    h2 acc[8];
#pragma unroll
    for (int i = 0; i < 8; ++i) acc[i] = z;
#pragma unroll
    for (int a = 0; a < 7; ++a) {
      const ushort* vrow = &sKV[((by + a) * 14 + bx) * 136 + h * 16 + 64];
#pragma unroll
      for (int c = 0; c < 7; ++c) {
        float p = __expf(s[a * 7 + c] - mx);
        l += p;
        h2 p2 = {(_Float16)p, (_Float16)p};
        const ushort* vp = vrow + c * 136;
        uint4 v0 = *(const uint4*)&vp[0];
        uint4 v1 = *(const uint4*)&vp[8];
        acc[0] = bch2(v0.x) * p2 + acc[0];
        acc[1] = bch2(v0.y) * p2 + acc[1];
        acc[2] = bch2(v0.z) * p2 + acc[2];
        acc[3] = bch2(v0.w) * p2 + acc[3];
        acc[4] = bch2(v1.x) * p2 + acc[4];
        acc[5] = bch2(v1.y) * p2 + acc[5];
        acc[6] = bch2(v1.z) * p2 + acc[6];
        acc[7] = bch2(v1.w) * p2 + acc[7];
      }
    }
    float inv = 1.f / l;
    __syncthreads();  // sKV dead; repurpose LDS
    ushort* sX  = sBuf;           // 64*72
    ushort* sH  = sBuf + 4608;    // 64*264
    ushort* x1f = sBuf + 21504;   // 64*72 (attn-out bf16, then x1 f16)
    uint32_t* ao = (uint32_t*)&x1f[pl * 72 + h * 16];
#pragma unroll
    for (int i = 0; i < 8; ++i)
      ao[i] = packbf((float)acc[i][0] * inv, (float)acc[i][1] * inv);
    __syncthreads();
    // ---- proj + residual -> x1 f16 in LDS (same region, own-wave rows) ----
    const ushort* Wp = wT + 41472 + br * 4608;
    int lr = lane & 15, lk = (lane >> 4) * 8;
    {
      int m0 = wid * 16;
      bf16x8 a0 = *(const bf16x8*)&x1f[(m0 + lr) * 72 + lk];
      bf16x8 a1 = *(const bf16x8*)&x1f[(m0 + lr) * 72 + 32 + lk];
      int r0 = m0 + (lane >> 4) * 4;
#pragma unroll
      for (int nt = 0; nt < 4; ++nt) {
        int n0 = nt * 16;
        bf16x8 b0 = *(const bf16x8*)&Wp[(n0 + lr) * 72 + lk];
        bf16x8 b1 = *(const bf16x8*)&Wp[(n0 + lr) * 72 + 32 + lk];
        f32x4 oacc = {0.f, 0.f, 0.f, 0.f};
        oacc = __builtin_amdgcn_mfma_f32_16x16x32_bf16(a0, b0, oacc, 0, 0, 0);
        oacc = __builtin_amdgcn_mfma_f32_16x16x32_bf16(a1, b1, oacc, 0, 0, 0);
        int col = n0 + lr;
        float bias = pb[br * 64 + col];
#pragma unroll
        for (int r = 0; r < 4; ++r) {
          int rr = r0 + r;
          int gp2 = b * 3136 + (y0 + (rr >> 3)) * 56 + (x0 + (rr & 7));
          x1f[rr * 72 + col] =
              f2h(oacc[r] + bias + x[(size_t)gp2 * 256 + br * 64 + col]);
        }
      }
    }
    __syncthreads();
    // ---- LN2 -> sX ----
    float g2 = nat_ln2_g[br * 64 + lane], b2l = nat_ln2_b[br * 64 + lane];
#pragma unroll
    for (int i = 0; i < 16; ++i) {
      int p = wid * 16 + i;
      float v = h2f(x1f[p * 72 + lane]);
      float s1 = wsum(v), s2 = wsum(v * v);
      float m = s1 * (1.f / 64.f);
      float var = s2 * (1.f / 64.f) - m * m;
      sX[p * 72 + lane] = f2bf((v - m) * rsqrtf(var + 1e-5f) * g2 + b2l);
    }
    __syncthreads();
    // ---- FC1 + GELU -> sH (swizzled) ----
    const ushort* W1 = wT + 55296 + br * 18432;
    const ushort* W2 = wT + 110592 + br * 16896;
    const float* B1 = nat_f1b + br * 256;
    const float* B2 = nat_f2b + br * 64;
    int mbase = (wid & 1) * 16;
    int r0 = (lane >> 4) * 4;
    bf16x8 a0m[2], a1m[2];
#pragma unroll
    for (int mh = 0; mh < 2; ++mh) {
      int m0 = mh * 32 + mbase;
      a0m[mh] = *(const bf16x8*)&sX[(m0 + lr) * 72 + lk];
      a1m[mh] = *(const bf16x8*)&sX[(m0 + lr) * 72 + 32 + lk];
    }
#pragma unroll
    for (int t2 = 0; t2 < 8; ++t2) {
      int n0 = ((wid >> 1) + 2 * t2) * 16;
      bf16x8 b0 = *(const bf16x8*)&W1[(n0 + lr) * 72 + lk];
      bf16x8 b1 = *(const bf16x8*)&W1[(n0 + lr) * 72 + 32 + lk];
      int col = n0 + lr;
      float b1v = B1[col];
#pragma unroll
      for (int mh = 0; mh < 2; ++mh) {
        f32x4 facc = {0.f, 0.f, 0.f, 0.f};
        facc = __builtin_amdgcn_mfma_f32_16x16x32_bf16(a0m[mh], b0, facc, 0, 0, 0);
        facc = __builtin_amdgcn_mfma_f32_16x16x32_bf16(a1m[mh], b1, facc, 0, 0, 0);
        int m0 = mh * 32 + mbase;
#pragma unroll
        for (int r = 0; r < 4; ++r) {
          int row = m0 + r0 + r;
          sH[row * 264 + (col ^ (((row >> 2) & 3) << 3))] =
              f2bf(gelu_fast(facc[r] + b1v));
        }
      }
    }
    __syncthreads();
    // ---- FC2 + residual -> out ----
#pragma unroll
    for (int mh = 0; mh < 2; ++mh) {
      int m0 = mh * 32 + mbase;
      bf16x8 af[8];
#pragma unroll
      for (int kb2 = 0; kb2 < 8; ++kb2) {
        int arow = m0 + lr;
        af[kb2] = *(const bf16x8*)&sH[arow * 264 +
                                      ((kb2 * 32 + lk) ^ (((arow >> 2) & 3) << 3))];
      }
#pragma unroll
      for (int u = 0; u < 2; ++u) {
        int n0 = ((wid >> 1) + 2 * u) * 16;
        f32x4 facc = {0.f, 0.f, 0.f, 0.f};
#pragma unroll
        for (int kb2 = 0; kb2 < 8; ++kb2) {
          bf16x8 bf = *(const bf16x8*)&W2[(n0 + lr) * 264 + kb2 * 32 + lk];
          facc = __builtin_amdgcn_mfma_f32_16x16x32_bf16(af[kb2], bf, facc, 0, 0, 0);
        }
        int col = n0 + lr;
        float b2v = B2[col];
#pragma unroll
        for (int r = 0; r < 4; ++r) {
          int p = m0 + r0 + r;
          int gp2 = b * 3136 + (y0 + (p >> 3)) * 56 + (x0 + (p & 7));
          out[(size_t)gp2 * 256 + br * 64 + col] =
              h2f(x1f[p * 72 + col]) + facc[r] + b2v;
        }
      }
    }
  } else {
    // GA attention: wave = q-tile
    int wt = (bid - 588) * 4 + wid;
    int bh = wt / 25, qt = wt % 25;
    int h = bh & 3, b = bh >> 2;
    int qrow = lane & 31, hi = lane >> 5;
    int dmod = lane & 15;
    const ushort* qbase = qb + (size_t)bh * 800 * 16;
    const ushort* kbase = kb + (size_t)bh * 800 * 16;
    const ushort* vbase = vT + (size_t)bh * 16 * 800 + (size_t)dmod * 800;
    bf16x8 qf = *(const bf16x8*)&qbase[(qt * 32 + qrow) * 16 + hi * 8];
    float m = -1e30f, l = 0.f;
    f32x16 acc_o;
#pragma unroll
    for (int r = 0; r < 16; ++r) acc_o[r] = 0.f;
    bf16x8 kf = *(const bf16x8*)&kbase[(0 + qrow) * 16 + hi * 8];
    bf16x8 vf0 = *(const bf16x8*)&vbase[0 + hi * 8];
    bf16x8 vf1 = *(const bf16x8*)&vbase[16 + hi * 8];
    for (int kt = 0; kt < 25; ++kt) {
      int nb = (kt < 24 ? kt + 1 : 24) * 32;
      bf16x8 nkf = *(const bf16x8*)&kbase[(nb + qrow) * 16 + hi * 8];
      bf16x8 nvf0 = *(const bf16x8*)&vbase[nb + hi * 8];
      bf16x8 nvf1 = *(const bf16x8*)&vbase[nb + 16 + hi * 8];
      f32x16 zero;
#pragma unroll
      for (int r = 0; r < 16; ++r) zero[r] = 0.f;
      f32x16 st = __builtin_amdgcn_mfma_f32_32x32x16_bf16(kf, qf, zero, 0, 0, 0);
      float s[16];
#pragma unroll
      for (int r = 0; r < 16; ++r) s[r] = st[r];
      if (kt == 24) {
#pragma unroll
        for (int r = 8; r < 16; ++r) s[r] = -1e30f;
      }
      float tm = s[0];
#pragma unroll
      for (int r = 1; r < 16; ++r) tm = fmaxf(tm, s[r]);
      tm = fmaxf(tm, __shfl_xor(tm, 32, 64));
      if (__any(tm > m + 8.f)) {
        float mn = fmaxf(m, tm);
        float sc = __expf(m - mn);
        l *= sc;
        m = mn;
#pragma unroll
        for (int r = 0; r < 16; ++r) {
          int row = (r & 3) + 4 * hi + 8 * (r >> 2);
          float scr = __shfl(sc, row, 64);
          acc_o[r] *= scr;
        }
      }
      uint32_t pk[8];
      float ps = 0.f;
#pragma unroll
      for (int i = 0; i < 8; ++i) {
        float p0 = __expf(s[2 * i] - m), p1 = __expf(s[2 * i + 1] - m);
        ps += p0 + p1;
        pk[i] = packbf(p0, p1);
      }
      l += ps;
#pragma unroll
      for (int t = 0; t < 2; ++t) {
        uint32_t c0 = pk[4 * t + 0], c1 = pk[4 * t + 1];
        uint32_t c2 = pk[4 * t + 2], c3 = pk[4 * t + 3];
        uint32_t b00 = __shfl((int)c0, qrow, 64), b02 = __shfl((int)c2, qrow, 64);
        uint32_t b10 = __shfl((int)c1, qrow, 64), b12 = __shfl((int)c3, qrow, 64);
        uint32_t b20 = __shfl((int)c0, qrow + 32, 64), b22 = __shfl((int)c2, qrow + 32, 64);
        uint32_t b30 = __shfl((int)c1, qrow + 32, 64), b32 = __shfl((int)c3, qrow + 32, 64);
        union { uint32_t u[4]; bf16x8 v; } pa;
        pa.u[0] = hi ? b02 : b00;
        pa.u[1] = hi ? b12 : b10;
        pa.u[2] = hi ? b22 : b20;
        pa.u[3] = hi ? b32 : b30;
        acc_o = __builtin_amdgcn_mfma_f32_32x32x16_bf16(pa.v, (t ? vf1 : vf0),
                                                        acc_o, 0, 0, 0);
      }
      kf = nkf; vf0 = nvf0; vf1 = nvf1;
    }
    l += __shfl_xor(l, 32, 64);
    float inv = 1.f / l;
#pragma unroll
    for (int r = 0; r < 16; ++r) {
      int row = (r & 3) + 4 * hi + 8 * (r >> 2);
      float invr = __shfl(inv, row, 64);
      int n = qt * 32 + row;
      if (n < 784 && qrow < 16) {
        float o = acc_o[r] * invr;
        int hp = n / 28, wp = n % 28;
        int ch = h * 16 + dmod;
#pragma unroll
        for (int dy = 0; dy < 2; ++dy)
#pragma unroll
          for (int dxx = 0; dxx < 2; ++dxx) {
            int pix = b * 3136 + (hp * 2 + dy) * 56 + (wp * 2 + dxx);
            x1g[(size_t)pix * 64 + ch] = x[(size_t)pix * 256 + 192 + ch] + o;
          }
      }
    }
  }
}

// ---------------- Kernel C: GA-only MLP (196 blocks) ----------------
__global__ __launch_bounds__(256) void k_mlp_ga(
    const float* __restrict__ x1g, const ushort* __restrict__ wT,
    const float* __restrict__ ga_ln2_g, const float* __restrict__ ga_ln2_b,
    const float* __restrict__ ga_f1b, const float* __restrict__ ga_f2b,
    float* __restrict__ out) {
  constexpr int H1 = 192;
  constexpr int K2P = 200;
  constexpr int KB = 6;
  __shared__ __align__(16) ushort sX[64 * 72];
  __shared__ __align__(16) ushort sH[64 * 200];
  int grp = blockIdx.x;
  int tid = threadIdx.x, lane = tid & 63, wid = tid >> 6;
  const ushort* W1 = wT + 175104;
  const ushort* W2 = wT + 188928;
  const float* xin = x1g + (size_t)(grp * 64) * 64;
  float g = ga_ln2_g[lane], bb = ga_ln2_b[lane];
#pragma unroll
  for (int i = 0; i < 16; ++i) {
    int pl = wid * 16 + i;
    float v = xin[pl * 64 + lane];
    float s1 = wsum(v), s2 = wsum(v * v);
    float m = s1 * (1.f / 64.f);
    float var = s2 * (1.f / 64.f) - m * m;
    sX[pl * 72 + lane] = f2bf((v - m) * rsqrtf(var + 1e-5f) * g + bb);
  }
  __syncthreads();
  int lr = lane & 15, lk = (lane >> 4) * 8;
  int mbase = (wid & 1) * 16;
  int r0 = (lane >> 4) * 4;
  bf16x8 a0[2], a1[2];
#pragma unroll
  for (int mh = 0; mh < 2; ++mh) {
    int m0 = mh * 32 + mbase;
    a0[mh] = *(const bf16x8*)&sX[(m0 + lr) * 72 + lk];
    a1[mh] = *(const bf16x8*)&sX[(m0 + lr) * 72 + 32 + lk];
  }
#pragma unroll
  for (int t2 = 0; t2 < H1 / 32; ++t2) {
    int n0 = ((wid >> 1) + 2 * t2) * 16;
    bf16x8 b0 = *(const bf16x8*)&W1[(n0 + lr) * 72 + lk];
    bf16x8 b1 = *(const bf16x8*)&W1[(n0 + lr) * 72 + 32 + lk];
    int col = n0 + lr;
    float b1v = ga_f1b[col];
#pragma unroll
    for (int mh = 0; mh < 2; ++mh) {
      f32x4 acc = {0.f, 0.f, 0.f, 0.f};
      acc = __builtin_amdgcn_mfma_f32_16x16x32_bf16(a0[mh], b0, acc, 0, 0, 0);
      acc = __builtin_amdgcn_mfma_f32_16x16x32_bf16(a1[mh], b1, acc, 0, 0, 0);
      int m0 = mh * 32 + mbase;
#pragma unroll
      for (int r = 0; r < 4; ++r) {
        int row = m0 + r0 + r;
        sH[row * K2P + (col ^ (((row >> 2) & 3) << 3))] =
            f2bf(gelu_fast(acc[r] + b1v));
      }
    }
  }
  __syncthreads();
#pragma unroll
  for (int mh = 0; mh < 2; ++mh) {
    int m0 = mh * 32 + mbase;
    bf16x8 af[KB];
#pragma unroll
    for (int kb = 0; kb < KB; ++kb) {
      int arow = m0 + lr;
      af[kb] = *(const bf16x8*)&sH[arow * K2P +
                                   ((kb * 32 + lk) ^ (((arow >> 2) & 3) << 3))];
    }
#pragma unroll
    for (int u = 0; u < 2; ++u) {
      int n0 = ((wid >> 1) + 2 * u) * 16;
      f32x4 acc = {0.f, 0.f, 0.f, 0.f};
#pragma unroll
      for (int kb = 0; kb < KB; ++kb) {
        bf16x8 bf = *(const bf16x8*)&W2[(n0 + lr) * K2P + kb * 32 + lk];
        acc = __builtin_amdgcn_mfma_f32_16x16x32_bf16(af[kb], bf, acc, 0, 0, 0);
      }
      int col = n0 + lr;
      float b2v = ga_f2b[col];
#pragma unroll
      for (int r = 0; r < 4; ++r) {
        int p = m0 + r0 + r;
        int pix = grp * 64 + p;
        out[(size_t)pix * 256 + 192 + col] = xin[p * 64 + col] + acc[r] + b2v;
      }
    }
  }
}

}  // namespace

extern "C" void kernel_launch(void* const* d_in, const int* in_sizes, int n_in,
                              void* d_out, int out_size, void* d_ws, size_t ws_size,
                              hipStream_t stream) {
  const float* x = (const float*)d_in[0];
  const float* nat_ln1_g = (const float*)d_in[1];
  const float* nat_ln1_b = (const float*)d_in[2];
  const float* nat_qkv_w = (const float*)d_in[3];
  const float* nat_qkv_b = (const float*)d_in[4];
  const float* nat_rpb = (const float*)d_in[5];
  const float* nat_proj_w = (const float*)d_in[6];
  const float* nat_proj_b = (const float*)d_in[7];
  const float* nat_ln2_g = (const float*)d_in[8];
  const float* nat_ln2_b = (const float*)d_in[9];
  const float* nat_fc1_w = (const float*)d_in[10];
  const float* nat_fc1_b = (const float*)d_in[11];
  const float* nat_fc2_w = (const float*)d_in[12];
  const float* nat_fc2_b = (const float*)d_in[13];
  const float* ga_ln1_g = (const float*)d_in[14];
  const float* ga_ln1_b = (const float*)d_in[15];
  const float* ga_qkv_w = (const float*)d_in[16];
  const float* ga_qkv_b = (const float*)d_in[17];
  const float* ga_ln2_g = (const float*)d_in[18];
  const float* ga_ln2_b = (const float*)d_in[19];
  const float* ga_fc1_w = (const float*)d_in[20];
  const float* ga_fc1_b = (const float*)d_in[21];
  const float* ga_fc2_w = (const float*)d_in[22];
  const float* ga_fc2_b = (const float*)d_in[23];

  uint8_t* w8 = (uint8_t*)d_ws;
  ushort* qn  = (ushort*)w8;                  //  4,816,896 B (f16)
  ushort* kvn = (ushort*)(w8 + 4816896);      //  9,633,792 B (f16)
  float*  x1g = (float*)(w8 + 14450688);      //  3,211,264 B (GA only)
  ushort* wT  = (ushort*)(w8 + 17661952);     //    403,456 B
  ushort* qgb = (ushort*)(w8 + 18065408);     //    409,600 B
  ushort* kgb = (ushort*)(w8 + 18475008);     //    409,600 B
  ushort* vgT = (ushort*)(w8 + 18884608);     //    409,600 B
  // total ~19.3 MB

  k_prep<<<dim3(789), dim3(256), 0, stream>>>(nat_qkv_w, nat_proj_w, nat_fc1_w,
                                              nat_fc2_w, ga_qkv_w, ga_fc1_w,
                                              ga_fc2_w, wT);
  k_qkv<<<dim3(638), dim3(256), 0, stream>>>(x, nat_ln1_g, nat_ln1_b, wT,
                                             nat_qkv_b, qn, kvn, ga_ln1_g,
                                             ga_ln1_b, ga_qkv_b, qgb, kgb, vgT);
  k_attn<<<dim3(688), dim3(256), 0, stream>>>(
      qn, kvn, nat_rpb, wT, nat_proj_b, x, nat_ln2_g, nat_ln2_b, nat_fc1_b,
      nat_fc2_b, (float*)d_out, qgb, kgb, vgT, x1g);
  k_mlp_ga<<<dim3(196), dim3(256), 0, stream>>>(x1g, wT, ga_ln2_g, ga_ln2_b,
                                                ga_fc1_b, ga_fc2_b,
                                                (float*)d_out);
}

// Round 13
// 85.194 us; speedup vs baseline: 1.0815x; 1.0815x over previous
//
#include <hip/hip_runtime.h>
#include <hip/hip_bf16.h>
#include <cstdint>

namespace {

constexpr int NPIX = 12544;   // 4*56*56

typedef __attribute__((ext_vector_type(8))) short bf16x8;
typedef __attribute__((ext_vector_type(4))) float f32x4;
typedef __attribute__((ext_vector_type(16))) float f32x16;
typedef _Float16 h2 __attribute__((ext_vector_type(2)));

__device__ __forceinline__ float wsum(float v) {
#pragma unroll
  for (int m = 32; m; m >>= 1) v += __shfl_xor(v, m, 64);
  return v;
}

__device__ __forceinline__ uint16_t f2bf(float f) {
  uint32_t u = __builtin_bit_cast(uint32_t, f);
  u += 0x7fffu + ((u >> 16) & 1u);
  return (uint16_t)(u >> 16);
}
__device__ __forceinline__ uint32_t packbf(float a, float b) {
  return (uint32_t)f2bf(a) | ((uint32_t)f2bf(b) << 16);
}
__device__ __forceinline__ ushort f2h(float f) {
  _Float16 h = (_Float16)f;
  return __builtin_bit_cast(ushort, h);
}
__device__ __forceinline__ h2 bch2(uint32_t u) { return __builtin_bit_cast(h2, u); }

__device__ __forceinline__ float gelu_fast(float v) {
  float u = 0.7978845608028654f * (v + 0.044715f * v * v * v);
  float e = __expf(2.f * u);
  float th = 1.f - 2.f * __builtin_amdgcn_rcpf(e + 1.f);
  return 0.5f * v * (1.f + th);
}

// ---------------- Prep: convert+transpose all weights to bf16 ----------------
__global__ __launch_bounds__(256) void k_prep(
    const float* __restrict__ nqkv, const float* __restrict__ nproj,
    const float* __restrict__ nf1, const float* __restrict__ nf2,
    const float* __restrict__ gqkv, const float* __restrict__ gf1,
    const float* __restrict__ gf2, ushort* __restrict__ wT) {
  int t = blockIdx.x * 256 + threadIdx.x;
  if (t >= 201728) return;
  int i = t;
  if (i < 41472) {
    int br = i / 13824, r = i % 13824, n = r / 72, k = r % 72;
    wT[t] = k < 64 ? f2bf(nqkv[(br * 64 + k) * 192 + n]) : (ushort)0;
    return;
  }
  i -= 41472;
  if (i < 13824) {
    int br = i / 4608, r = i % 4608, n = r / 72, k = r % 72;
    wT[t] = k < 64 ? f2bf(nproj[(br * 64 + k) * 64 + n]) : (ushort)0;
    return;
  }
  i -= 13824;
  if (i < 55296) {
    int br = i / 18432, r = i % 18432, n = r / 72, k = r % 72;
    wT[t] = k < 64 ? f2bf(nf1[(br * 64 + k) * 256 + n]) : (ushort)0;
    return;
  }
  i -= 55296;
  if (i < 50688) {
    int br = i / 16896, r = i % 16896, n = r / 264, k = r % 264;
    wT[t] = k < 256 ? f2bf(nf2[(br * 256 + k) * 64 + n]) : (ushort)0;
    return;
  }
  i -= 50688;
  if (i < 13824) {
    int n = i / 72, k = i % 72;
    wT[t] = k < 64 ? f2bf(gqkv[k * 192 + n]) : (ushort)0;
    return;
  }
  i -= 13824;
  if (i < 13824) {
    int n = i / 72, k = i % 72;
    wT[t] = k < 64 ? f2bf(gf1[k * 192 + n]) : (ushort)0;
    return;
  }
  i -= 13824;
  {
    int n = i / 200, k = i % 200;
    wT[t] = k < 192 ? f2bf(gf2[k * 64 + n]) : (ushort)0;
  }
}

// ---------------- Kernel A: fused QKV — NAT (0..587) | GA (588..636) | pad (637)
__global__ __launch_bounds__(256) void k_qkv(
    const float* __restrict__ x, const float* __restrict__ nat_ln1_g,
    const float* __restrict__ nat_ln1_b, const ushort* __restrict__ wT,
    const float* __restrict__ nat_qkv_b, ushort* __restrict__ qn,
    ushort* __restrict__ kvn, const float* __restrict__ ga_ln1_g,
    const float* __restrict__ ga_ln1_b, const float* __restrict__ ga_qkv_b,
    ushort* __restrict__ qb, ushort* __restrict__ kb, ushort* __restrict__ vT) {
  __shared__ __align__(16) ushort sA[64 * 72];
  int bid = blockIdx.x;
  int tid = threadIdx.x, lane = tid & 63, wid = tid >> 6;
  if (bid == 637) {
    for (int i = tid; i < 4096; i += 256) {
      int bh = i >> 8, rem = i & 255;
      int n = 784 + (rem >> 4), d = rem & 15;
      qb[((size_t)bh * 800 + n) * 16 + d] = 0;
      kb[((size_t)bh * 800 + n) * 16 + d] = 0;
      vT[((size_t)bh * 16 + d) * 800 + n] = 0;
    }
    return;
  }
  int lr = lane & 15, lk = (lane >> 4) * 8;
  if (bid < 588) {  // NAT LN1 + QKV
    int br = bid / 196, grp = bid % 196;
    const ushort* Wg = wT + br * 13824;
    float g = nat_ln1_g[br * 64 + lane], bb = nat_ln1_b[br * 64 + lane];
#pragma unroll
    for (int i = 0; i < 16; ++i) {
      int pl = wid * 16 + i;
      float v = x[(size_t)(grp * 64 + pl) * 256 + br * 64 + lane];
      float s1 = wsum(v), s2 = wsum(v * v);
      float m = s1 * (1.f / 64.f);
      float var = s2 * (1.f / 64.f) - m * m;
      sA[pl * 72 + lane] = f2bf((v - m) * rsqrtf(var + 1e-5f) * g + bb);
    }
    __syncthreads();
    int m0 = wid * 16;
    bf16x8 a0 = *(const bf16x8*)&sA[(m0 + lr) * 72 + lk];
    bf16x8 a1 = *(const bf16x8*)&sA[(m0 + lr) * 72 + 32 + lk];
    int r0 = m0 + (lane >> 4) * 4;
#pragma unroll
    for (int nt = 0; nt < 12; ++nt) {
      int n0 = nt * 16;
      bf16x8 b0 = *(const bf16x8*)&Wg[(n0 + lr) * 72 + lk];
      bf16x8 b1 = *(const bf16x8*)&Wg[(n0 + lr) * 72 + 32 + lk];
      f32x4 acc = {0.f, 0.f, 0.f, 0.f};
      acc = __builtin_amdgcn_mfma_f32_16x16x32_bf16(a0, b0, acc, 0, 0, 0);
      acc = __builtin_amdgcn_mfma_f32_16x16x32_bf16(a1, b1, acc, 0, 0, 0);
      int col = n0 + lr;
      float bias = nat_qkv_b[br * 192 + col];
      if (nt < 4) {
        ushort* op = qn + ((size_t)br * NPIX + grp * 64 + r0) * 64 + col;
#pragma unroll
        for (int r = 0; r < 4; ++r) op[r * 64] = f2h((acc[r] + bias) * 0.25f);
      } else {
        ushort* op = kvn + ((size_t)br * NPIX + grp * 64 + r0) * 128 + (col - 64);
#pragma unroll
        for (int r = 0; r < 4; ++r) op[r * 128] = f2h(acc[r] + bias);
      }
    }
  } else {  // GA pool+LN + QKV via MFMA (49 blocks x 64 tokens)
    int g64 = bid - 588;
    const ushort* Wg = wT + 161280;
    float gg = ga_ln1_g[lane], bb = ga_ln1_b[lane];
#pragma unroll
    for (int i = 0; i < 16; ++i) {
      int tl = wid * 16 + i;
      int token = g64 * 64 + tl;
      int b = token / 784, rem2 = token % 784, hp = rem2 / 28, wp = rem2 % 28;
      float s = 0.f;
#pragma unroll
      for (int dy = 0; dy < 2; ++dy)
#pragma unroll
        for (int dxx = 0; dxx < 2; ++dxx) {
          int pix = b * 3136 + (hp * 2 + dy) * 56 + (wp * 2 + dxx);
          float v = x[(size_t)pix * 256 + 192 + lane];
          float s1 = wsum(v), s2 = wsum(v * v);
          float m = s1 * (1.f / 64.f);
          float var = s2 * (1.f / 64.f) - m * m;
          s += (v - m) * rsqrtf(var + 1e-5f) * gg + bb;
        }
      sA[tl * 72 + lane] = f2bf(0.25f * s);
    }
    __syncthreads();
    int m0 = wid * 16;
    bf16x8 a0 = *(const bf16x8*)&sA[(m0 + lr) * 72 + lk];
    bf16x8 a1 = *(const bf16x8*)&sA[(m0 + lr) * 72 + 32 + lk];
    int r0 = m0 + (lane >> 4) * 4;
#pragma unroll
    for (int nt = 0; nt < 12; ++nt) {
      int n0 = nt * 16;
      bf16x8 b0 = *(const bf16x8*)&Wg[(n0 + lr) * 72 + lk];
      bf16x8 b1 = *(const bf16x8*)&Wg[(n0 + lr) * 72 + 32 + lk];
      f32x4 acc = {0.f, 0.f, 0.f, 0.f};
      acc = __builtin_amdgcn_mfma_f32_16x16x32_bf16(a0, b0, acc, 0, 0, 0);
      acc = __builtin_amdgcn_mfma_f32_16x16x32_bf16(a1, b1, acc, 0, 0, 0);
      int col = n0 + lr;
      float bias = ga_qkv_b[col];
      int hh = (col & 63) >> 4, d = col & 15;
#pragma unroll
      for (int r = 0; r < 4; ++r) {
        int token = g64 * 64 + r0 + r;
        int b = token / 784, nn = token % 784;
        float v = acc[r] + bias;
        if (col < 64)
          qb[((size_t)(b * 4 + hh) * 800 + nn) * 16 + d] = f2bf(v * 0.25f);
        else if (col < 128)
          kb[((size_t)(b * 4 + hh) * 800 + nn) * 16 + d] = f2bf(v);
        else
          vT[((size_t)(b * 4 + hh) * 16 + d) * 800 + nn] = f2bf(v);
      }
    }
  }
}

// ---------------- Kernel B: fused attention ----------------
// NAT: K staged first (28.2 KB), scores; then V re-staged into SAME buffer.
__global__ __launch_bounds__(256) void k_attn(
    const ushort* __restrict__ qn, const ushort* __restrict__ kvn,
    const float* __restrict__ rpb, const ushort* __restrict__ wT,
    const float* __restrict__ pb, const float* __restrict__ x,
    float* __restrict__ x1, const ushort* __restrict__ qb,
    const ushort* __restrict__ kb, const ushort* __restrict__ vT,
    float* __restrict__ x1g) {
  __shared__ __align__(16) ushort sBuf[196 * 72];  // 28,224 B -> 5 blocks/CU
  int bid = blockIdx.x;
  int tid = threadIdx.x, lane = tid & 63, wid = tid >> 6;
  if (bid < 588) {
    ushort* sK = sBuf;
    int br = bid / 196, rem = bid % 196;
    int b = rem / 49, t = rem % 49;
    int y0 = (t / 7) * 8, x0 = (t % 7) * 8;
    int hy = min(max(y0 - 3, 0), 42), hx = min(max(x0 - 3, 0), 42);
    const ushort* kvbase = kvn + ((size_t)br * NPIX + b * 3136) * 128;
    // ---- stage K (196 rows x 64 ushorts -> stride 72) ----
    for (int i = tid; i < 1568; i += 256) {
      int p = i >> 3, c = i & 7;
      int py = p / 14, px = p % 14;
      int gp = (hy + py) * 56 + (hx + px);
      *(uint4*)&sK[p * 72 + c * 8] =
          *(const uint4*)&kvbase[(size_t)gp * 128 + c * 8];
    }
    __syncthreads();
    int pl = tid & 63, h = tid >> 6;
    int ly = pl >> 3, lx = pl & 7;
    int y = y0 + ly, xg = x0 + lx;
    int sy = min(max(y - 3, 0), 49), sx = min(max(xg - 3, 0), 49);
    int by = sy - hy, bx = sx - hx;
    int gpix = b * 3136 + y * 56 + xg;
    const ushort* qp = qn + ((size_t)br * NPIX + gpix) * 64 + h * 16;
    uint4 qv0 = *(const uint4*)&qp[0];
    uint4 qv1 = *(const uint4*)&qp[8];
    h2 q[8] = {bch2(qv0.x), bch2(qv0.y), bch2(qv0.z), bch2(qv0.w),
               bch2(qv1.x), bch2(qv1.y), bch2(qv1.z), bch2(qv1.w)};
    const float* rp = rpb + (br * 4 + h) * 169 + (sy - y + 6) * 13 + (sx - xg + 6);
    h2 z = {(_Float16)0.f, (_Float16)0.f};
    // pass 1: all 49 scores into registers + exact max
    float s[49];
    float mx = -1e30f;
#pragma unroll
    for (int a = 0; a < 7; ++a) {
      const ushort* krow = &sK[((by + a) * 14 + bx) * 72 + h * 16];
      const float* rpa = rp + a * 13;
#pragma unroll
      for (int c = 0; c < 7; ++c) {
        const ushort* kp = krow + c * 72;
        uint4 k0 = *(const uint4*)&kp[0];
        uint4 k1 = *(const uint4*)&kp[8];
        h2 d = z;
        d = bch2(k0.x) * q[0] + d;
        d = bch2(k0.y) * q[1] + d;
        d = bch2(k0.z) * q[2] + d;
        d = bch2(k0.w) * q[3] + d;
        d = bch2(k1.x) * q[4] + d;
        d = bch2(k1.y) * q[5] + d;
        d = bch2(k1.z) * q[6] + d;
        d = bch2(k1.w) * q[7] + d;
        float sd = (float)d[0] + (float)d[1] + rpa[c];
        s[a * 7 + c] = sd;
        mx = fmaxf(mx, sd);
      }
    }
    __syncthreads();  // all K reads done; overwrite with V
    for (int i = tid; i < 1568; i += 256) {
      int p = i >> 3, c = i & 7;
      int py = p / 14, px = p % 14;
      int gp = (hy + py) * 56 + (hx + px);
      *(uint4*)&sK[p * 72 + c * 8] =
          *(const uint4*)&kvbase[(size_t)gp * 128 + 64 + c * 8];
    }
    __syncthreads();
    // pass 2: independent exps + V accumulation
    float l = 0.f;
    h2 acc[8];
#pragma unroll
    for (int i = 0; i < 8; ++i) acc[i] = z;
#pragma unroll
    for (int a = 0; a < 7; ++a) {
      const ushort* vrow = &sK[((by + a) * 14 + bx) * 72 + h * 16];
#pragma unroll
      for (int c = 0; c < 7; ++c) {
        float p = __expf(s[a * 7 + c] - mx);
        l += p;
        h2 p2 = {(_Float16)p, (_Float16)p};
        const ushort* vp = vrow + c * 72;
        uint4 v0 = *(const uint4*)&vp[0];
        uint4 v1 = *(const uint4*)&vp[8];
        acc[0] = bch2(v0.x) * p2 + acc[0];
        acc[1] = bch2(v0.y) * p2 + acc[1];
        acc[2] = bch2(v0.z) * p2 + acc[2];
        acc[3] = bch2(v0.w) * p2 + acc[3];
        acc[4] = bch2(v1.x) * p2 + acc[4];
        acc[5] = bch2(v1.y) * p2 + acc[5];
        acc[6] = bch2(v1.z) * p2 + acc[6];
        acc[7] = bch2(v1.w) * p2 + acc[7];
      }
    }
    float inv = 1.f / l;
    __syncthreads();  // V reads done; repurpose as sAp
    ushort* sAp = sBuf;
    uint32_t* ao = (uint32_t*)&sAp[pl * 72 + h * 16];
#pragma unroll
    for (int i = 0; i < 8; ++i)
      ao[i] = packbf((float)acc[i][0] * inv, (float)acc[i][1] * inv);
    __syncthreads();
    const ushort* Wp = wT + 41472 + br * 4608;
    int lr = lane & 15, lk = (lane >> 4) * 8;
    int m0 = wid * 16;
    bf16x8 a0 = *(const bf16x8*)&sAp[(m0 + lr) * 72 + lk];
    bf16x8 a1 = *(const bf16x8*)&sAp[(m0 + lr) * 72 + 32 + lk];
    int r0 = m0 + (lane >> 4) * 4;
#pragma unroll
    for (int nt = 0; nt < 4; ++nt) {
      int n0 = nt * 16;
      bf16x8 b0 = *(const bf16x8*)&Wp[(n0 + lr) * 72 + lk];
      bf16x8 b1 = *(const bf16x8*)&Wp[(n0 + lr) * 72 + 32 + lk];
      f32x4 oacc = {0.f, 0.f, 0.f, 0.f};
      oacc = __builtin_amdgcn_mfma_f32_16x16x32_bf16(a0, b0, oacc, 0, 0, 0);
      oacc = __builtin_amdgcn_mfma_f32_16x16x32_bf16(a1, b1, oacc, 0, 0, 0);
      int col = n0 + lr;
      float bias = pb[br * 64 + col];
#pragma unroll
      for (int r = 0; r < 4; ++r) {
        int rr = r0 + r;
        int gp2 = b * 3136 + (y0 + (rr >> 3)) * 56 + (x0 + (rr & 7));
        x1[((size_t)br * NPIX + gp2) * 64 + col] =
            oacc[r] + bias + x[(size_t)gp2 * 256 + br * 64 + col];
      }
    }
  } else {
    // GA attention: wave = q-tile
    int wt = (bid - 588) * 4 + wid;
    int bh = wt / 25, qt = wt % 25;
    int h = bh & 3, b = bh >> 2;
    int qrow = lane & 31, hi = lane >> 5;
    int dmod = lane & 15;
    const ushort* qbase = qb + (size_t)bh * 800 * 16;
    const ushort* kbase = kb + (size_t)bh * 800 * 16;
    const ushort* vbase = vT + (size_t)bh * 16 * 800 + (size_t)dmod * 800;
    bf16x8 qf = *(const bf16x8*)&qbase[(qt * 32 + qrow) * 16 + hi * 8];
    float m = -1e30f, l = 0.f;
    f32x16 acc_o;
#pragma unroll
    for (int r = 0; r < 16; ++r) acc_o[r] = 0.f;
    bf16x8 kf = *(const bf16x8*)&kbase[(0 + qrow) * 16 + hi * 8];
    bf16x8 vf0 = *(const bf16x8*)&vbase[0 + hi * 8];
    bf16x8 vf1 = *(const bf16x8*)&vbase[16 + hi * 8];
    for (int kt = 0; kt < 25; ++kt) {
      int nb = (kt < 24 ? kt + 1 : 24) * 32;
      bf16x8 nkf = *(const bf16x8*)&kbase[(nb + qrow) * 16 + hi * 8];
      bf16x8 nvf0 = *(const bf16x8*)&vbase[nb + hi * 8];
      bf16x8 nvf1 = *(const bf16x8*)&vbase[nb + 16 + hi * 8];
      f32x16 zero;
#pragma unroll
      for (int r = 0; r < 16; ++r) zero[r] = 0.f;
      f32x16 st = __builtin_amdgcn_mfma_f32_32x32x16_bf16(kf, qf, zero, 0, 0, 0);
      float s[16];
#pragma unroll
      for (int r = 0; r < 16; ++r) s[r] = st[r];
      if (kt == 24) {
#pragma unroll
        for (int r = 8; r < 16; ++r) s[r] = -1e30f;
      }
      float tm = s[0];
#pragma unroll
      for (int r = 1; r < 16; ++r) tm = fmaxf(tm, s[r]);
      tm = fmaxf(tm, __shfl_xor(tm, 32, 64));
      if (__any(tm > m + 8.f)) {
        float mn = fmaxf(m, tm);
        float sc = __expf(m - mn);
        l *= sc;
        m = mn;
#pragma unroll
        for (int r = 0; r < 16; ++r) {
          int row = (r & 3) + 4 * hi + 8 * (r >> 2);
          float scr = __shfl(sc, row, 64);
          acc_o[r] *= scr;
        }
      }
      uint32_t pk[8];
      float ps = 0.f;
#pragma unroll
      for (int i = 0; i < 8; ++i) {
        float p0 = __expf(s[2 * i] - m), p1 = __expf(s[2 * i + 1] - m);
        ps += p0 + p1;
        pk[i] = packbf(p0, p1);
      }
      l += ps;
#pragma unroll
      for (int t = 0; t < 2; ++t) {
        uint32_t c0 = pk[4 * t + 0], c1 = pk[4 * t + 1];
        uint32_t c2 = pk[4 * t + 2], c3 = pk[4 * t + 3];
        uint32_t b00 = __shfl((int)c0, qrow, 64), b02 = __shfl((int)c2, qrow, 64);
        uint32_t b10 = __shfl((int)c1, qrow, 64), b12 = __shfl((int)c3, qrow, 64);
        uint32_t b20 = __shfl((int)c0, qrow + 32, 64), b22 = __shfl((int)c2, qrow + 32, 64);
        uint32_t b30 = __shfl((int)c1, qrow + 32, 64), b32 = __shfl((int)c3, qrow + 32, 64);
        union { uint32_t u[4]; bf16x8 v; } pa;
        pa.u[0] = hi ? b02 : b00;
        pa.u[1] = hi ? b12 : b10;
        pa.u[2] = hi ? b22 : b20;
        pa.u[3] = hi ? b32 : b30;
        acc_o = __builtin_amdgcn_mfma_f32_32x32x16_bf16(pa.v, (t ? vf1 : vf0),
                                                        acc_o, 0, 0, 0);
      }
      kf = nkf; vf0 = nvf0; vf1 = nvf1;
    }
    l += __shfl_xor(l, 32, 64);
    float inv = 1.f / l;
#pragma unroll
    for (int r = 0; r < 16; ++r) {
      int row = (r & 3) + 4 * hi + 8 * (r >> 2);
      float invr = __shfl(inv, row, 64);
      int n = qt * 32 + row;
      if (n < 784 && qrow < 16) {
        float o = acc_o[r] * invr;
        int hp = n / 28, wp = n % 28;
        int ch = h * 16 + dmod;
#pragma unroll
        for (int dy = 0; dy < 2; ++dy)
#pragma unroll
          for (int dxx = 0; dxx < 2; ++dxx) {
            int pix = b * 3136 + (hp * 2 + dy) * 56 + (wp * 2 + dxx);
            x1g[(size_t)pix * 64 + ch] = x[(size_t)pix * 256 + 192 + ch] + o;
          }
      }
    }
  }
}

// ---------------- Kernel C: fused MLP (weights direct; sH XOR-swizzled) -----
template <bool NAT>
__device__ __forceinline__ void mlp_body(
    int br, int grp, ushort* sX, ushort* sH,
    const float* __restrict__ x1, const ushort* __restrict__ W1,
    const ushort* __restrict__ W2, const float* __restrict__ B1,
    const float* __restrict__ B2, const float* __restrict__ G,
    const float* __restrict__ Bt, float* __restrict__ out) {
  constexpr int H1 = NAT ? 256 : 192;
  constexpr int K2P = NAT ? 264 : 200;
  constexpr int KB = H1 / 32;
  int tid = threadIdx.x, lane = tid & 63, wid = tid >> 6;
  const float* xin = x1 + ((size_t)br * NPIX + grp * 64) * 64;
  float g = G[lane], bb = Bt[lane];
#pragma unroll
  for (int i = 0; i < 16; ++i) {
    int pl = wid * 16 + i;
    float v = xin[pl * 64 + lane];
    float s1 = wsum(v), s2 = wsum(v * v);
    float m = s1 * (1.f / 64.f);
    float var = s2 * (1.f / 64.f) - m * m;
    sX[pl * 72 + lane] = f2bf((v - m) * rsqrtf(var + 1e-5f) * g + bb);
  }
  __syncthreads();
  int lr = lane & 15, lk = (lane >> 4) * 8;
  int mbase = (wid & 1) * 16;
  int r0 = (lane >> 4) * 4;
  bf16x8 a0[2], a1[2];
#pragma unroll
  for (int mh = 0; mh < 2; ++mh) {
    int m0 = mh * 32 + mbase;
    a0[mh] = *(const bf16x8*)&sX[(m0 + lr) * 72 + lk];
    a1[mh] = *(const bf16x8*)&sX[(m0 + lr) * 72 + 32 + lk];
  }
#pragma unroll
  for (int t2 = 0; t2 < H1 / 32; ++t2) {
    int n0 = ((wid >> 1) + 2 * t2) * 16;
    bf16x8 b0 = *(const bf16x8*)&W1[(n0 + lr) * 72 + lk];
    bf16x8 b1 = *(const bf16x8*)&W1[(n0 + lr) * 72 + 32 + lk];
    int col = n0 + lr;
    float b1v = B1[col];
#pragma unroll
    for (int mh = 0; mh < 2; ++mh) {
      f32x4 acc = {0.f, 0.f, 0.f, 0.f};
      acc = __builtin_amdgcn_mfma_f32_16x16x32_bf16(a0[mh], b0, acc, 0, 0, 0);
      acc = __builtin_amdgcn_mfma_f32_16x16x32_bf16(a1[mh], b1, acc, 0, 0, 0);
      int m0 = mh * 32 + mbase;
#pragma unroll
      for (int r = 0; r < 4; ++r) {
        int row = m0 + r0 + r;
        sH[row * K2P + (col ^ (((row >> 2) & 3) << 3))] =
            f2bf(gelu_fast(acc[r] + b1v));
      }
    }
  }
  __syncthreads();
#pragma unroll
  for (int mh = 0; mh < 2; ++mh) {
    int m0 = mh * 32 + mbase;
    bf16x8 af[KB];
#pragma unroll
    for (int kb = 0; kb < KB; ++kb) {
      int arow = m0 + lr;
      af[kb] = *(const bf16x8*)&sH[arow * K2P +
                                   ((kb * 32 + lk) ^ (((arow >> 2) & 3) << 3))];
    }
#pragma unroll
    for (int u = 0; u < 2; ++u) {
      int n0 = ((wid >> 1) + 2 * u) * 16;
      f32x4 acc = {0.f, 0.f, 0.f, 0.f};
#pragma unroll
      for (int kb = 0; kb < KB; ++kb) {
        bf16x8 bf = *(const bf16x8*)&W2[(n0 + lr) * K2P + kb * 32 + lk];
        acc = __builtin_amdgcn_mfma_f32_16x16x32_bf16(af[kb], bf, acc, 0, 0, 0);
      }
      int col = n0 + lr;
      float b2v = B2[col];
#pragma unroll
      for (int r = 0; r < 4; ++r) {
        int p = m0 + r0 + r;
        int pix = grp * 64 + p;
        out[(size_t)pix * 256 + br * 64 + col] = xin[p * 64 + col] + acc[r] + b2v;
      }
    }
  }
}

__global__ __launch_bounds__(256) void k_mlp(
    const float* __restrict__ x1, const float* __restrict__ nat_ln2_g,
    const float* __restrict__ nat_ln2_b, const ushort* __restrict__ wT,
    const float* __restrict__ nat_f1b, const float* __restrict__ nat_f2b,
    const float* __restrict__ ga_ln2_g, const float* __restrict__ ga_ln2_b,
    const float* __restrict__ ga_f1b, const float* __restrict__ ga_f2b,
    float* __restrict__ out) {
  __shared__ __align__(16) ushort sX[64 * 72];
  __shared__ __align__(16) ushort sH[64 * 264];
  int bid = blockIdx.x;
  if (bid < 588) {
    int br = bid / 196, grp = bid % 196;
    mlp_body<true>(br, grp, sX, sH, x1, wT + 55296 + br * 18432,
                   wT + 110592 + br * 16896, nat_f1b + br * 256,
                   nat_f2b + br * 64, nat_ln2_g + br * 64, nat_ln2_b + br * 64,
                   out);
  } else {
    int grp = bid - 588;
    mlp_body<false>(3, grp, sX, sH, x1, wT + 175104, wT + 188928, ga_f1b,
                    ga_f2b, ga_ln2_g, ga_ln2_b, out);
  }
}

}  // namespace

extern "C" void kernel_launch(void* const* d_in, const int* in_sizes, int n_in,
                              void* d_out, int out_size, void* d_ws, size_t ws_size,
                              hipStream_t stream) {
  const float* x = (const float*)d_in[0];
  const float* nat_ln1_g = (const float*)d_in[1];
  const float* nat_ln1_b = (const float*)d_in[2];
  const float* nat_qkv_w = (const float*)d_in[3];
  const float* nat_qkv_b = (const float*)d_in[4];
  const float* nat_rpb = (const float*)d_in[5];
  const float* nat_proj_w = (const float*)d_in[6];
  const float* nat_proj_b = (const float*)d_in[7];
  const float* nat_ln2_g = (const float*)d_in[8];
  const float* nat_ln2_b = (const float*)d_in[9];
  const float* nat_fc1_w = (const float*)d_in[10];
  const float* nat_fc1_b = (const float*)d_in[11];
  const float* nat_fc2_w = (const float*)d_in[12];
  const float* nat_fc2_b = (const float*)d_in[13];
  const float* ga_ln1_g = (const float*)d_in[14];
  const float* ga_ln1_b = (const float*)d_in[15];
  const float* ga_qkv_w = (const float*)d_in[16];
  const float* ga_qkv_b = (const float*)d_in[17];
  const float* ga_ln2_g = (const float*)d_in[18];
  const float* ga_ln2_b = (const float*)d_in[19];
  const float* ga_fc1_w = (const float*)d_in[20];
  const float* ga_fc1_b = (const float*)d_in[21];
  const float* ga_fc2_w = (const float*)d_in[22];
  const float* ga_fc2_b = (const float*)d_in[23];

  uint8_t* w8 = (uint8_t*)d_ws;
  ushort* qn  = (ushort*)w8;                  //  4,816,896 B (f16)
  ushort* kvn = (ushort*)(w8 + 4816896);      //  9,633,792 B (f16)
  float*  x1  = (float*)(w8 + 14450688);      // 12,845,056 B
  ushort* wT  = (ushort*)(w8 + 27295744);     //    403,456 B
  ushort* qgb = (ushort*)(w8 + 27699200);     //    409,600 B
  ushort* kgb = (ushort*)(w8 + 28108800);     //    409,600 B
  ushort* vgT = (ushort*)(w8 + 28518400);     //    409,600 B

  k_prep<<<dim3(789), dim3(256), 0, stream>>>(nat_qkv_w, nat_proj_w, nat_fc1_w,
                                              nat_fc2_w, ga_qkv_w, ga_fc1_w,
                                              ga_fc2_w, wT);
  k_qkv<<<dim3(638), dim3(256), 0, stream>>>(x, nat_ln1_g, nat_ln1_b, wT,
                                             nat_qkv_b, qn, kvn, ga_ln1_g,
                                             ga_ln1_b, ga_qkv_b, qgb, kgb, vgT);
  k_attn<<<dim3(688), dim3(256), 0, stream>>>(qn, kvn, nat_rpb, wT, nat_proj_b,
                                              x, x1, qgb, kgb, vgT,
                                              x1 + (size_t)3 * NPIX * 64);
  k_mlp<<<dim3(784), dim3(256), 0, stream>>>(x1, nat_ln2_g, nat_ln2_b, wT,
                                             nat_fc1_b, nat_fc2_b, ga_ln2_g,
                                             ga_ln2_b, ga_fc1_b, ga_fc2_b,
                                             (float*)d_out);
}